// Round 1
// baseline (1093.956 us; speedup 1.0000x reference)
//
#include <hip/hip_runtime.h>

// Problem constants
#define NN   10000
#define EE   40000
#define FIN  128
#define CC   32
#define EDIM 4000

// ---------------- workspace layout (float offsets) ----------------
// zeroed region (one hipMemsetAsync):
#define OFF_CNT      0        // int[10240]
#define OFF_EA1      10240    // float[E]
#define OFF_EA2      50240
#define OFF_SEA1     90240    // float[N] (padded 10240)
#define OFF_SEA2     100480
#define OFF_DEN1     110720
#define OFF_DEN2     120960
#define OFF_AGG1     131200   // float[N*32]
#define OFF_AGG2     451200
#define ZERO_FLOATS  771200
// non-zeroed:
#define OFF_SRC      771200   // int[E] (padded 40960)
#define OFF_DST      812160
#define OFF_H1       853120   // float[N*32]
#define OFF_HS1      1173120
#define OFF_HD1      1183360
#define OFF_P1       1193600  // float[E] (padded 40960)
#define OFF_PL1      1234560
#define OFF_Z1       1244800
#define OFF_H2       1564800
#define OFF_HS2      1884800
#define OFF_HD2      1895040
#define OFF_P2       1905280
#define OFF_PL2      1946240

// ---------------- edge index detect + convert + histogram ----------------
__global__ __launch_bounds__(256) void detect_convert(
    const void* __restrict__ ei, int* __restrict__ srcI, int* __restrict__ dstI,
    int* __restrict__ cnt)
{
    const int* w = (const int*)ei;
    // int64 layout iff high words of first 8 values are all zero
    bool is64 = ((w[1] | w[3] | w[5] | w[7] | w[9] | w[11] | w[13] | w[15]) == 0);
    int i = blockIdx.x * 256 + threadIdx.x;
    if (i < EE) {
        int s, d;
        if (is64) {
            const long long* e64 = (const long long*)ei;
            s = (int)e64[i];
            d = (int)e64[EE + i];
        } else {
            s = w[i];
            d = w[EE + i];
        }
        srcI[i] = s;
        dstI[i] = d;
        atomicAdd(&cnt[d], 1);
    }
}

// ---------------- big fused GEMM: [E,4000] @ [4000, 32|32] -> ea1[E], ea2[E] ----------------
// 64x64 tile, BK=64, 4x4 micro-tile, split-K over blockIdx.y (4 ranges of 16 chunks; 63 chunks total)
__global__ __launch_bounds__(256) void edge_gemm(
    const float* __restrict__ EA,
    const float* __restrict__ We1, const float* __restrict__ We2,
    const float* __restrict__ ae1, const float* __restrict__ ae2,
    float* __restrict__ ea1g, float* __restrict__ ea2g)
{
    __shared__ __align__(16) float As[64][68];  // [kk][m], padded
    __shared__ __align__(16) float Bs[64][68];  // [kk][n], padded

    const int t    = threadIdx.x;
    const int row0 = blockIdx.x * 64;           // E=40000 divisible by 64
    const int c0   = blockIdx.y * 16;
    const int c1   = min(c0 + 16, 63);          // 63 chunks cover K=4000 (last partial)

    const int tm = t >> 4, tn = t & 15;         // 16x16 thread grid
    const int lrow = t >> 2, ls = t & 3;        // staging: 4 threads per row

    float acc[4][4] = {};

    const float* Arow = EA + (size_t)(row0 + lrow) * EDIM;

    for (int ch = c0; ch < c1; ++ch) {
        const int k0 = ch * 64;
        // stage A (transposed to k-major)
        #pragma unroll
        for (int j = 0; j < 4; ++j) {
            int kk = 4 * (ls + 4 * j);
            int kg = k0 + kk;
            float4 v = make_float4(0.f, 0.f, 0.f, 0.f);
            if (kg < EDIM) v = *(const float4*)(Arow + kg);
            As[kk + 0][lrow] = v.x;
            As[kk + 1][lrow] = v.y;
            As[kk + 2][lrow] = v.z;
            As[kk + 3][lrow] = v.w;
        }
        // stage B (already k-major; cols 0..31 = We1, 32..63 = We2)
        {
            int kg = k0 + lrow;
            #pragma unroll
            for (int j = 0; j < 4; ++j) {
                int col4 = 4 * (ls + 4 * j);
                float4 v = make_float4(0.f, 0.f, 0.f, 0.f);
                if (kg < EDIM) {
                    const float* src = (col4 < 32)
                        ? (We1 + (size_t)kg * 32 + col4)
                        : (We2 + (size_t)kg * 32 + (col4 - 32));
                    v = *(const float4*)src;
                }
                *(float4*)&Bs[lrow][col4] = v;
            }
        }
        __syncthreads();
        #pragma unroll 4
        for (int kk = 0; kk < 64; ++kk) {
            float4 a4 = *(float4*)&As[kk][tm << 2];
            float4 b4 = *(float4*)&Bs[kk][tn << 2];
            float av[4] = {a4.x, a4.y, a4.z, a4.w};
            float bv[4] = {b4.x, b4.y, b4.z, b4.w};
            #pragma unroll
            for (int i = 0; i < 4; ++i)
                #pragma unroll
                for (int j = 0; j < 4; ++j)
                    acc[i][j] += av[i] * bv[j];
        }
        __syncthreads();
    }

    // epilogue: row-dot with a_e, reduce across tn within block, atomicAdd to ea (split-K)
    float* red = &As[0][0];                      // 128 floats scratch
    if (t < 128) red[t] = 0.f;
    __syncthreads();
    const int half = tn >> 3;                    // 0 -> layer1 cols, 1 -> layer2 cols
    const int colL = (tn << 2) - (half << 5);    // col within layer (0..28)
    const float* ae = half ? ae2 : ae1;
    const float a0 = ae[colL], a1 = ae[colL + 1], a2 = ae[colL + 2], a3 = ae[colL + 3];
    #pragma unroll
    for (int i = 0; i < 4; ++i) {
        float sP = acc[i][0] * a0 + acc[i][1] * a1 + acc[i][2] * a2 + acc[i][3] * a3;
        atomicAdd(&red[(((tm << 2) + i) << 1) + half], sP);
    }
    __syncthreads();
    if (t < 128) {
        int row = t >> 1, hh = t & 1;
        float* dstp = hh ? ea2g : ea1g;
        atomicAdd(&dstp[row0 + row], red[t]);
    }
}

// ---------------- scatter sum_ea[dst] += ea[e] (both layers) ----------------
__global__ __launch_bounds__(256) void scatter_sum_ea(
    const int* __restrict__ dstI,
    const float* __restrict__ ea1, const float* __restrict__ ea2,
    float* __restrict__ se1, float* __restrict__ se2)
{
    int i = blockIdx.x * 256 + threadIdx.x;
    if (i < EE) {
        int d = dstI[i];
        atomicAdd(&se1[d], ea1[i]);
        atomicAdd(&se2[d], ea2[i]);
    }
}

// ---------------- node transform: h = X @ W; hs = h@a_src; hd = h@a_dst ----------------
template <int K>
__global__ __launch_bounds__(256) void node_transform(
    const float* __restrict__ X, const float* __restrict__ Wg,
    const float* __restrict__ a_src, const float* __restrict__ a_dst,
    float* __restrict__ h, float* __restrict__ hs, float* __restrict__ hd)
{
    __shared__ __align__(16) float Wl[K * 32];
    __shared__ __align__(16) float Xl[64][K];
    __shared__ float Hl[64][33];

    const int t = threadIdx.x;
    const int row0 = blockIdx.x * 64;

    for (int idx = t; idx < K * 8; idx += 256)
        ((float4*)Wl)[idx] = ((const float4*)Wg)[idx];
    for (int idx = t; idx < 64 * (K / 4); idx += 256) {
        int r = idx / (K / 4), kq = idx % (K / 4);
        int gr = row0 + r;
        float4 v = make_float4(0.f, 0.f, 0.f, 0.f);
        if (gr < NN) v = ((const float4*)(X + (size_t)gr * K))[kq];
        *(float4*)&Xl[r][kq * 4] = v;
    }
    __syncthreads();

    const int c = t & 31, rb = t >> 5;
    #pragma unroll
    for (int j = 0; j < 8; ++j) {
        int r = rb * 8 + j;
        float accv = 0.f;
        for (int k = 0; k < K; ++k) accv += Xl[r][k] * Wl[k * 32 + c];
        Hl[r][c] = accv;
        int gr = row0 + r;
        if (gr < NN) h[(size_t)gr * 32 + c] = accv;
    }
    __syncthreads();

    if (t < 64) {
        int gr = row0 + t;
        if (gr < NN) {
            float s1 = 0.f, s2 = 0.f;
            #pragma unroll
            for (int cc = 0; cc < 32; ++cc) {
                float hv = Hl[t][cc];
                s1 += hv * a_src[cc];
                s2 += hv * a_dst[cc];
            }
            hs[gr] = s1;
            hd[gr] = s2;
        }
    }
}

// ---------------- edge softmax numerators + denominators ----------------
// items [0,E): real edges; [E, E+N): self loops
__global__ __launch_bounds__(256) void edge_softmax(
    const int* __restrict__ srcI, const int* __restrict__ dstI,
    const float* __restrict__ hs, const float* __restrict__ hd,
    const float* __restrict__ ea, const float* __restrict__ sum_ea,
    const int* __restrict__ cnt,
    float* __restrict__ pe, float* __restrict__ ploop, float* __restrict__ denom)
{
    int i = blockIdx.x * 256 + threadIdx.x;
    if (i < EE) {
        int s = srcI[i], d = dstI[i];
        float a = hs[s] + hd[d] + ea[i];
        a = a > 0.f ? a : 0.2f * a;          // leaky relu
        float p = expf(a);                   // max-shift skipped: softmax-invariant, |a| ~ O(1)
        pe[i] = p;
        atomicAdd(&denom[d], p);
    } else if (i < EE + NN) {
        int n = i - EE;
        float cf = (float)cnt[n];
        cf = cf < 1.f ? 1.f : cf;
        float a = hs[n] + hd[n] + sum_ea[n] / cf;
        a = a > 0.f ? a : 0.2f * a;
        float p = expf(a);
        ploop[n] = p;
        atomicAdd(&denom[n], p);
    }
}

// ---------------- weighted scatter aggregation: agg[d,:] += p * h[s,:] ----------------
__global__ __launch_bounds__(256) void aggregate(
    const int* __restrict__ srcI, const int* __restrict__ dstI,
    const float* __restrict__ h, const float* __restrict__ pe,
    const float* __restrict__ ploop, float* __restrict__ agg)
{
    int gid = blockIdx.x * 256 + threadIdx.x;
    int i = gid >> 3;
    int c4 = (gid & 7) << 2;
    if (i >= EE + NN) return;
    int s, d;
    float p;
    if (i < EE) {
        s = srcI[i]; d = dstI[i]; p = pe[i];
    } else {
        s = d = i - EE; p = ploop[s];
    }
    const float4 hv = *(const float4*)&h[(size_t)s * 32 + c4];
    float* ag = &agg[(size_t)d * 32 + c4];
    atomicAdd(ag + 0, p * hv.x);
    atomicAdd(ag + 1, p * hv.y);
    atomicAdd(ag + 2, p * hv.z);
    atomicAdd(ag + 3, p * hv.w);
}

// ---------------- finalize: out = agg/denom + b (optional relu) ----------------
__global__ __launch_bounds__(256) void finalize(
    const float* __restrict__ agg, const float* __restrict__ denom,
    const float* __restrict__ bias, float* __restrict__ out, int relu)
{
    int gid = blockIdx.x * 256 + threadIdx.x;
    if (gid >= NN * 32) return;
    int n = gid >> 5, cidx = gid & 31;
    float v = agg[gid] / (denom[n] + 1e-16f) + bias[cidx];
    if (relu) v = v > 0.f ? v : 0.f;
    out[gid] = v;
}

// ---------------- host launcher ----------------
extern "C" void kernel_launch(void* const* d_in, const int* in_sizes, int n_in,
                              void* d_out, int out_size, void* d_ws, size_t ws_size,
                              hipStream_t stream)
{
    const float* x    = (const float*)d_in[0];
    const void*  ei   = d_in[1];
    const float* eatt = (const float*)d_in[2];
    const float* W1   = (const float*)d_in[3];
    const float* as1  = (const float*)d_in[4];
    const float* ad1  = (const float*)d_in[5];
    const float* We1  = (const float*)d_in[6];
    const float* ae1  = (const float*)d_in[7];
    const float* b1   = (const float*)d_in[8];
    const float* W2   = (const float*)d_in[9];
    const float* as2  = (const float*)d_in[10];
    const float* ad2  = (const float*)d_in[11];
    const float* We2  = (const float*)d_in[12];
    const float* ae2  = (const float*)d_in[13];
    const float* b2   = (const float*)d_in[14];
    float* out = (float*)d_out;
    float* w   = (float*)d_ws;

    // zero accumulators (cnt, ea, sum_ea, denom, agg)
    hipMemsetAsync(d_ws, 0, (size_t)ZERO_FLOATS * 4, stream);

    int*   cnt  = (int*)(w + OFF_CNT);
    float* ea1v = w + OFF_EA1;
    float* ea2v = w + OFF_EA2;
    float* sea1 = w + OFF_SEA1;
    float* sea2 = w + OFF_SEA2;
    float* den1 = w + OFF_DEN1;
    float* den2 = w + OFF_DEN2;
    float* agg1 = w + OFF_AGG1;
    float* agg2 = w + OFF_AGG2;
    int*   srcI = (int*)(w + OFF_SRC);
    int*   dstI = (int*)(w + OFF_DST);
    float* h1   = w + OFF_H1;
    float* hs1  = w + OFF_HS1;
    float* hd1  = w + OFF_HD1;
    float* p1   = w + OFF_P1;
    float* pl1  = w + OFF_PL1;
    float* z1   = w + OFF_Z1;
    float* h2   = w + OFF_H2;
    float* hs2  = w + OFF_HS2;
    float* hd2  = w + OFF_HD2;
    float* p2   = w + OFF_P2;
    float* pl2  = w + OFF_PL2;

    detect_convert<<<157, 256, 0, stream>>>(ei, srcI, dstI, cnt);

    // big fused GEMM (both layers' edge projections -> scalar ea per edge)
    edge_gemm<<<dim3(625, 4), 256, 0, stream>>>(eatt, We1, We2, ae1, ae2, ea1v, ea2v);
    scatter_sum_ea<<<157, 256, 0, stream>>>(dstI, ea1v, ea2v, sea1, sea2);

    // layer 1
    node_transform<128><<<157, 256, 0, stream>>>(x, W1, as1, ad1, h1, hs1, hd1);
    edge_softmax<<<196, 256, 0, stream>>>(srcI, dstI, hs1, hd1, ea1v, sea1, cnt, p1, pl1, den1);
    aggregate<<<1563, 256, 0, stream>>>(srcI, dstI, h1, p1, pl1, agg1);
    finalize<<<1250, 256, 0, stream>>>(agg1, den1, b1, z1, 1);

    // layer 2
    node_transform<32><<<157, 256, 0, stream>>>(z1, W2, as2, ad2, h2, hs2, hd2);
    edge_softmax<<<196, 256, 0, stream>>>(srcI, dstI, hs2, hd2, ea2v, sea2, cnt, p2, pl2, den2);
    aggregate<<<1563, 256, 0, stream>>>(srcI, dstI, h2, p2, pl2, agg2);
    finalize<<<1250, 256, 0, stream>>>(agg2, den2, b2, out, 0);
}

// Round 2
// 916.740 us; speedup vs baseline: 1.1933x; 1.1933x over previous
//
#include <hip/hip_runtime.h>

// Problem constants
#define NN   10000
#define EE   40000
#define FIN  128
#define CC   32
#define EDIM 4000

// ---------------- workspace layout (float offsets) ----------------
// zeroed region (one hipMemsetAsync):
#define OFF_CNT      0        // int[10240]
#define OFF_SEA1     10240    // float[N] pad 10240
#define OFF_SEA2     20480
#define OFF_DEN1     30720
#define OFF_DEN2     40960
#define OFF_AGG1     51200    // float[N*32]
#define OFF_AGG2     371200
#define ZERO_FLOATS  691200
// non-zeroed:
#define OFF_SRC      691200   // int[E] pad 40960
#define OFF_DST      732160
#define OFF_EA1      773120   // float[E] pad 40960
#define OFF_EA2      814080
#define OFF_W1V      855040   // float[4096]
#define OFF_W2V      859136
#define OFF_H1       863232   // float[N*32]
#define OFF_HS1      1183232
#define OFF_HD1      1193472
#define OFF_Z1       1203712
#define OFF_H2       1523712
#define OFF_HS2      1843712
#define OFF_HD2      1853952

// ---------------- edge index detect + convert + in-degree histogram ----------------
__global__ __launch_bounds__(256) void detect_convert(
    const void* __restrict__ ei, int* __restrict__ srcI, int* __restrict__ dstI,
    int* __restrict__ cnt)
{
    const int* w = (const int*)ei;
    // int64 layout iff high words of first 8 values are all zero (indices < 10000)
    bool is64 = ((w[1] | w[3] | w[5] | w[7] | w[9] | w[11] | w[13] | w[15]) == 0);
    int i = blockIdx.x * 256 + threadIdx.x;
    if (i < EE) {
        int s, d;
        if (is64) {
            const long long* e64 = (const long long*)ei;
            s = (int)e64[i];
            d = (int)e64[EE + i];
        } else {
            s = w[i];
            d = w[EE + i];
        }
        srcI[i] = s;
        dstI[i] = d;
        atomicAdd(&cnt[d], 1);
    }
}

// ---------------- w = We @ a_e for both layers (4000-vector each) ----------------
__global__ __launch_bounds__(256) void weight_vec(
    const float* __restrict__ We1, const float* __restrict__ ae1,
    const float* __restrict__ We2, const float* __restrict__ ae2,
    float* __restrict__ w1, float* __restrict__ w2)
{
    __shared__ float a1s[32], a2s[32];
    if (threadIdx.x < 32) {
        a1s[threadIdx.x] = ae1[threadIdx.x];
        a2s[threadIdx.x] = ae2[threadIdx.x];
    }
    __syncthreads();
    int k = blockIdx.x * 256 + threadIdx.x;
    if (k >= EDIM) return;
    const float* r1 = We1 + (size_t)k * 32;
    const float* r2 = We2 + (size_t)k * 32;
    float s1 = 0.f, s2 = 0.f;
    #pragma unroll
    for (int c4 = 0; c4 < 8; ++c4) {
        float4 v1 = ((const float4*)r1)[c4];
        float4 v2 = ((const float4*)r2)[c4];
        float4 a1 = *(const float4*)&a1s[c4 * 4];
        float4 a2 = *(const float4*)&a2s[c4 * 4];
        s1 += v1.x * a1.x + v1.y * a1.y + v1.z * a1.z + v1.w * a1.w;
        s2 += v2.x * a2.x + v2.y * a2.y + v2.z * a2.z + v2.w * a2.w;
    }
    w1[k] = s1;
    w2[k] = s2;
}

// ---------------- ea[e] = edge_attr[e]·w (both layers), fused sea scatter ----------------
// One wave per edge, 16 edges per block. HBM-bound: reads edge_attr (640 MB) once.
__global__ __launch_bounds__(256) void edge_dot(
    const float* __restrict__ EA,
    const float* __restrict__ w1, const float* __restrict__ w2,
    const int* __restrict__ dstI,
    float* __restrict__ ea1, float* __restrict__ ea2,
    float* __restrict__ sea1, float* __restrict__ sea2)
{
    __shared__ __align__(16) float W1s[4000];
    __shared__ __align__(16) float W2s[4000];
    const int t = threadIdx.x;
    for (int i = t; i < 1000; i += 256) {
        ((float4*)W1s)[i] = ((const float4*)w1)[i];
        ((float4*)W2s)[i] = ((const float4*)w2)[i];
    }
    __syncthreads();
    const int wv = t >> 6, l = t & 63;
    const int base = blockIdx.x * 16;
    #pragma unroll
    for (int ee = 0; ee < 4; ++ee) {
        const int e = base + ee * 4 + wv;
        const float* A = EA + (size_t)e * EDIM;
        float acc1 = 0.f, acc2 = 0.f;
        #pragma unroll 5
        for (int j = 0; j < 15; ++j) {
            int idx = j * 256 + l * 4;
            float4 a = *(const float4*)(A + idx);
            float4 u = *(const float4*)(W1s + idx);
            float4 v = *(const float4*)(W2s + idx);
            acc1 += a.x * u.x + a.y * u.y + a.z * u.z + a.w * u.w;
            acc2 += a.x * v.x + a.y * v.y + a.z * v.z + a.w * v.w;
        }
        if (l < 40) {  // tail: floats 3840..3999
            int idx = 3840 + l * 4;
            float4 a = *(const float4*)(A + idx);
            float4 u = *(const float4*)(W1s + idx);
            float4 v = *(const float4*)(W2s + idx);
            acc1 += a.x * u.x + a.y * u.y + a.z * u.z + a.w * u.w;
            acc2 += a.x * v.x + a.y * v.y + a.z * v.z + a.w * v.w;
        }
        #pragma unroll
        for (int m = 32; m >= 1; m >>= 1) {
            acc1 += __shfl_xor(acc1, m);
            acc2 += __shfl_xor(acc2, m);
        }
        if (l == 0) {
            ea1[e] = acc1;
            ea2[e] = acc2;
            int d = dstI[e];
            atomicAdd(&sea1[d], acc1);
            atomicAdd(&sea2[d], acc2);
        }
    }
}

// ---------------- node transform: h = X @ W; hs = h@a_src; hd = h@a_dst ----------------
template <int K>
__global__ __launch_bounds__(256) void node_transform(
    const float* __restrict__ X, const float* __restrict__ Wg,
    const float* __restrict__ a_src, const float* __restrict__ a_dst,
    float* __restrict__ h, float* __restrict__ hs, float* __restrict__ hd)
{
    constexpr int SW = K + 4;                    // stride ≡4 mod 32: ≤4-way on the one Wt read
    __shared__ __align__(16) float Wt[32][SW];   // W transposed: Wt[c][k]
    __shared__ __align__(16) float Xl[64][K];
    __shared__ float Hl[64][33];

    const int t = threadIdx.x;
    const int row0 = blockIdx.x * 64;

    for (int idx = t; idx < 32 * K; idx += 256) {
        int c = idx & 31, k = idx >> 5;
        Wt[c][k] = Wg[idx];
    }
    for (int idx = t; idx < 64 * (K / 4); idx += 256) {
        int r = idx / (K / 4), kq = idx % (K / 4);
        int gr = row0 + r;
        float4 v = make_float4(0.f, 0.f, 0.f, 0.f);
        if (gr < NN) v = ((const float4*)(X + (size_t)gr * K))[kq];
        *(float4*)&Xl[r][kq * 4] = v;
    }
    __syncthreads();

    const int c = t & 31, rb = t >> 5;           // thread: col c, rows rb*8..rb*8+7
    float acc[8] = {};
    #pragma unroll 4
    for (int k4 = 0; k4 < K / 4; ++k4) {
        float4 wv = *(const float4*)&Wt[c][k4 * 4];
        #pragma unroll
        for (int j = 0; j < 8; ++j) {
            float4 xv = *(const float4*)&Xl[rb * 8 + j][k4 * 4];
            acc[j] += xv.x * wv.x + xv.y * wv.y + xv.z * wv.z + xv.w * wv.w;
        }
    }
    #pragma unroll
    for (int j = 0; j < 8; ++j) {
        int r = rb * 8 + j, gr = row0 + r;
        Hl[r][c] = acc[j];
        if (gr < NN) h[(size_t)gr * 32 + c] = acc[j];
    }
    __syncthreads();

    if (t < 64) {
        int gr = row0 + t;
        if (gr < NN) {
            float s1 = 0.f, s2 = 0.f;
            #pragma unroll
            for (int cc = 0; cc < 32; ++cc) {
                float hv = Hl[t][cc];
                s1 += hv * a_src[cc];
                s2 += hv * a_dst[cc];
            }
            hs[gr] = s1;
            hd[gr] = s2;
        }
    }
}

// ---------------- fused softmax-numerator + weighted scatter aggregation ----------------
// items [0,E): real edges; [E,E+N): self loops. 8 threads per item (4 channels each).
// Division by denom is deferred to finalize, so unnormalized p is correct.
__global__ __launch_bounds__(256) void attn_agg(
    const int* __restrict__ srcI, const int* __restrict__ dstI,
    const float* __restrict__ hs, const float* __restrict__ hd,
    const float* __restrict__ ea, const float* __restrict__ sea,
    const int* __restrict__ cnt, const float* __restrict__ h,
    float* __restrict__ denom, float* __restrict__ agg)
{
    int gid = blockIdx.x * 256 + threadIdx.x;
    int i = gid >> 3, sub = gid & 7;
    if (i >= EE + NN) return;
    int s, d;
    float extra;
    if (i < EE) {
        s = srcI[i];
        d = dstI[i];
        extra = ea[i];
    } else {
        s = d = i - EE;
        float cf = (float)cnt[s];
        extra = sea[s] / (cf < 1.f ? 1.f : cf);
    }
    float a = hs[s] + hd[d] + extra;
    a = a > 0.f ? a : 0.2f * a;                  // leaky relu
    float p = expf(a);                           // max-shift skipped: softmax-invariant, |a|~O(1)
    if (sub == 0) atomicAdd(&denom[d], p);
    const float4 hv = *(const float4*)&h[(size_t)s * 32 + sub * 4];
    float* ag = &agg[(size_t)d * 32 + sub * 4];
    atomicAdd(ag + 0, p * hv.x);
    atomicAdd(ag + 1, p * hv.y);
    atomicAdd(ag + 2, p * hv.z);
    atomicAdd(ag + 3, p * hv.w);
}

// ---------------- finalize: out = agg/denom + b (optional relu) ----------------
__global__ __launch_bounds__(256) void finalize(
    const float* __restrict__ agg, const float* __restrict__ denom,
    const float* __restrict__ bias, float* __restrict__ out, int relu)
{
    int gid = blockIdx.x * 256 + threadIdx.x;
    if (gid >= NN * 32) return;
    int n = gid >> 5, cidx = gid & 31;
    float v = agg[gid] / (denom[n] + 1e-16f) + bias[cidx];
    if (relu) v = v > 0.f ? v : 0.f;
    out[gid] = v;
}

// ---------------- host launcher ----------------
extern "C" void kernel_launch(void* const* d_in, const int* in_sizes, int n_in,
                              void* d_out, int out_size, void* d_ws, size_t ws_size,
                              hipStream_t stream)
{
    const float* x    = (const float*)d_in[0];
    const void*  ei   = d_in[1];
    const float* eatt = (const float*)d_in[2];
    const float* W1   = (const float*)d_in[3];
    const float* as1  = (const float*)d_in[4];
    const float* ad1  = (const float*)d_in[5];
    const float* We1  = (const float*)d_in[6];
    const float* ae1  = (const float*)d_in[7];
    const float* b1   = (const float*)d_in[8];
    const float* W2   = (const float*)d_in[9];
    const float* as2  = (const float*)d_in[10];
    const float* ad2  = (const float*)d_in[11];
    const float* We2  = (const float*)d_in[12];
    const float* ae2  = (const float*)d_in[13];
    const float* b2   = (const float*)d_in[14];
    float* out = (float*)d_out;
    float* w   = (float*)d_ws;

    // zero accumulators (cnt, sea, denom, agg)
    hipMemsetAsync(d_ws, 0, (size_t)ZERO_FLOATS * 4, stream);

    int*   cnt  = (int*)(w + OFF_CNT);
    float* sea1 = w + OFF_SEA1;
    float* sea2 = w + OFF_SEA2;
    float* den1 = w + OFF_DEN1;
    float* den2 = w + OFF_DEN2;
    float* agg1 = w + OFF_AGG1;
    float* agg2 = w + OFF_AGG2;
    int*   srcI = (int*)(w + OFF_SRC);
    int*   dstI = (int*)(w + OFF_DST);
    float* ea1v = w + OFF_EA1;
    float* ea2v = w + OFF_EA2;
    float* w1v  = w + OFF_W1V;
    float* w2v  = w + OFF_W2V;
    float* h1   = w + OFF_H1;
    float* hs1  = w + OFF_HS1;
    float* hd1  = w + OFF_HD1;
    float* z1   = w + OFF_Z1;
    float* h2   = w + OFF_H2;
    float* hs2  = w + OFF_HS2;
    float* hd2  = w + OFF_HD2;

    detect_convert<<<157, 256, 0, stream>>>(ei, srcI, dstI, cnt);
    weight_vec<<<16, 256, 0, stream>>>(We1, ae1, We2, ae2, w1v, w2v);

    // ea[e] = edge_attr[e]·(We@ae)  — the only pass over the 640 MB edge_attr
    edge_dot<<<2500, 256, 0, stream>>>(eatt, w1v, w2v, dstI, ea1v, ea2v, sea1, sea2);

    // layer 1
    node_transform<128><<<157, 256, 0, stream>>>(x, W1, as1, ad1, h1, hs1, hd1);
    attn_agg<<<1563, 256, 0, stream>>>(srcI, dstI, hs1, hd1, ea1v, sea1, cnt, h1, den1, agg1);
    finalize<<<1250, 256, 0, stream>>>(agg1, den1, b1, z1, 1);

    // layer 2
    node_transform<32><<<157, 256, 0, stream>>>(z1, W2, as2, ad2, h2, hs2, hd2);
    attn_agg<<<1563, 256, 0, stream>>>(srcI, dstI, hs2, hd2, ea2v, sea2, cnt, h2, den2, agg2);
    finalize<<<1250, 256, 0, stream>>>(agg2, den2, b2, out, 0);
}